// Round 4
// baseline (117.113 us; speedup 1.0000x reference)
//
#include <hip/hip_runtime.h>

// Problem constants
#define HW_   36864      // 192*192
#define WI    192
#define HT    192
#define CIN   128
#define DK    256        // == D_V
#define NH    8
#define DKH   32         // channels per head
// TEMPER = 16 -> scale 1/16 = 0.0625

using short4_ = __attribute__((ext_vector_type(4))) short;
using short8  = __attribute__((ext_vector_type(8))) short;
using float4_ = __attribute__((ext_vector_type(4))) float;

static __device__ __forceinline__ float b2f(unsigned short u) {
    union { unsigned int i; float f; } x; x.i = ((unsigned int)u) << 16; return x.f;
}
static __device__ __forceinline__ unsigned short f2b(float f) {
    union { float f; unsigned int i; } x; x.f = f;
    unsigned int r = x.i + 0x7FFFu + ((x.i >> 16) & 1u);   // round-nearest-even
    return (unsigned short)(r >> 16);
}

// ---------------------------------------------------------------------------
// Kernel 1: weights fp32 -> bf16 wqkv[8][96][128], interleaved row layout
// per head (verified r1):
//   rows  0-15 : q[ 0:16]   rows 16-31 : k[ 0:16]   rows 32-47 : v[ 0:16]
//   rows 48-63 : q[16:32]   rows 64-79 : k[16:32]   rows 80-95 : v[16:32]
// (UNCHANGED)
// ---------------------------------------------------------------------------
__global__ __launch_bounds__(256) void convw_kernel(
    const float* __restrict__ wq,
    const float* __restrict__ wk,
    const float* __restrict__ wv,
    unsigned short* __restrict__ wqkv)
{
    int id = blockIdx.x * 256 + threadIdx.x;   // 98304 = 8*96*128
    int h   = id / 12288;
    int rem = id - h * 12288;
    int r   = rem >> 7;                        // 0..95
    int c   = rem & 127;
    int g   = r >> 4;                          // 0..5
    int gm  = g % 3;                           // 0=q 1=k 2=v
    int rr  = ((g >= 3) ? 16 : 0) + (r & 15);  // channel within head half
    const float* __restrict__ s = (gm == 0) ? wq : ((gm == 1) ? wk : wv);
    wqkv[id] = f2b(s[(h * 32 + rr) * 128 + c]);
}

// ---------------------------------------------------------------------------
// Kernel 2 (FUSED projection + softmax + gather):
//   grid 512 = 256 px-tiles (24x6 interior, 26x8=208 halo px = 13 exact
//   MFMA n-tiles) x 2 head-groups (4 heads each). Eliminates vbuf+sbuf
//   HBM round-trips entirely.
//   - Bs: halo pixels staged once (stride-136 verified layout), reused 4x.
//   - A-fragments read DIRECTLY from L2-hot wqkv into registers (no A-LDS);
//     next head's fragments prefetched right after last use (T14).
//   - Per head: MFMA (r3-verified pattern) -> scores partial + bf16 V into
//     LDS (Sc/Vt) -> barrier -> softmax+gather (op-identical to the r4/r6/r7
//     verified math) -> direct fp32 out stores.
//   - wn waves duplicate n-tile 6 (identical bytes written twice: benign)
//     to keep all register arrays statically indexed.
// LDS = 74.9 KB -> 2 blocks/CU. 2 barriers per head.
// ---------------------------------------------------------------------------
__global__ __launch_bounds__(256) void fusedattn_kernel(
    const float* __restrict__ x,               // [128][HW] fp32
    const unsigned short* __restrict__ wqkv,   // [8][96][128] bf16 (interleaved)
    float* __restrict__ out)                   // [256][HW] fp32
{
    __shared__ __align__(16) unsigned short Bs[208 * 136]; // 56576 B halo pixels
    __shared__ __align__(16) unsigned short Vt[208 * 40];  // 16640 B v (bf16), stride 40
    __shared__ float Sc[2][208];                           // 1664 B q.k partials

    const int blk   = blockIdx.x;              // 512 = 256 tiles * 2 head-groups
    const int hbase = (blk & 1) * 4;
    const int tile  = blk >> 1;
    const int ty = tile >> 3, tx = tile & 7;   // 32 x 8 tile grid
    const int y0 = ty * 6, x0 = tx * 24;
    const int t    = threadIdx.x;
    const int lane = t & 63, wave = t >> 6;
    const int col  = lane & 15, quad = lane >> 4;
    const int wm   = wave >> 1, wn = wave & 1;
    const int ntb  = wn * 6;                   // n-tiles 0..6 / 6..12

    // ---- prefetch head hbase A-fragments straight into registers ----
    short8 a[3][4];
    {
        const unsigned short* __restrict__ Ag = wqkv + hbase * 12288;
        #pragma unroll
        for (int mt = 0; mt < 3; ++mt)
            #pragma unroll
            for (int kt = 0; kt < 4; ++kt)
                a[mt][kt] = *(const short8*)&Ag[(wm * 48 + mt * 16 + col) * 128 + kt * 32 + quad * 8];
    }

    // ---- stage Bs: 208 halo px x 128 ch; thread t<208 owns one px ----
    if (t < 208) {
        int hy = t / 26, hx = t - hy * 26;
        int gy = y0 - 1 + hy; gy = gy < 0 ? 0 : (gy > HT - 1 ? HT - 1 : gy);
        int gx = x0 - 1 + hx; gx = gx < 0 ? 0 : (gx > WI - 1 ? WI - 1 : gx);
        const float* __restrict__ xp = x + gy * WI + gx;
        unsigned short* bp = Bs + t * 136;
        #pragma unroll 8
        for (int c = 0; c < 128; ++c)
            bp[c] = f2b(xp[(size_t)c * HW_]);
    }
    __syncthreads();                           // Bs ready

    for (int hh = 0; hh < 4; ++hh) {
        const int head = hbase + hh;

        // ---- MFMA: acc[mt][j], mt: 0=q 1=k 2=v chunk of this wm half ----
        float4_ acc[3][7];
        #pragma unroll
        for (int mt = 0; mt < 3; ++mt)
            #pragma unroll
            for (int j = 0; j < 7; ++j)
                acc[mt][j] = (float4_){0.f, 0.f, 0.f, 0.f};

        #pragma unroll
        for (int j = 0; j < 7; ++j) {
            const int p = (ntb + j) * 16 + col;
            short8 bb[4];
            #pragma unroll
            for (int kt = 0; kt < 4; ++kt)
                bb[kt] = *(const short8*)&Bs[p * 136 + kt * 32 + quad * 8];
            #pragma unroll
            for (int mt = 0; mt < 3; ++mt)
                #pragma unroll
                for (int kt = 0; kt < 4; ++kt)
                    acc[mt][j] = __builtin_amdgcn_mfma_f32_16x16x32_bf16(a[mt][kt], bb[kt], acc[mt][j], 0, 0, 0);
        }

        // ---- prefetch next head's A-fragments (a[] last used above) ----
        if (hh < 3) {
            const unsigned short* __restrict__ Ag = wqkv + (head + 1) * 12288;
            #pragma unroll
            for (int mt = 0; mt < 3; ++mt)
                #pragma unroll
                for (int kt = 0; kt < 4; ++kt)
                    a[mt][kt] = *(const short8*)&Ag[(wm * 48 + mt * 16 + col) * 128 + kt * 32 + quad * 8];
        }

        // ---- epilogue: scores partial + v (bf16) into LDS ----
        // (previous head's gather finished at the loop-end barrier)
        #pragma unroll
        for (int j = 0; j < 7; ++j) {
            const int p = (ntb + j) * 16 + col;
            float s = 0.f;
            #pragma unroll
            for (int reg = 0; reg < 4; ++reg)
                s += acc[0][j][reg] * acc[1][j][reg];    // q.k partial (16 dk of wm)
            s += __shfl_xor(s, 16, 64);
            s += __shfl_xor(s, 32, 64);
            if (quad == 0) Sc[wm][p] = s;
            short4_ v0;
            #pragma unroll
            for (int reg = 0; reg < 4; ++reg)
                v0[reg] = (short)f2b(acc[2][j][reg]);
            *(short4_*)&Vt[p * 40 + wm * 16 + quad * 4] = v0;
        }
        __syncthreads();                       // Sc/Vt ready

        // ---- softmax + gather + direct out (verified math, op-identical) ----
        for (int idx = t; idx < 288; idx += 256) {
            const int pxl = idx >> 1;          // 0..143 interior px
            const int hg  = idx & 1;           // 16-channel half
            const int ly  = pxl / 24, lx = pxl - ly * 24;
            const int y   = y0 + ly, xx = x0 + lx;

            float w[9];
            float m = -1e30f;
            #pragma unroll
            for (int r = 0; r < 9; ++r) {
                int dy = r / 3 - 1, dx = r % 3 - 1;
                int ny = y + dy, nx = xx + dx;
                bool inb = (ny >= 0) && (ny < HT) && (nx >= 0) && (nx < WI);
                int hp = (ly + 1 + dy) * 26 + lx + 1 + dx;
                float val = inb ? ((Sc[0][hp] + Sc[1][hp]) * 0.0625f) : 0.0f;
                w[r] = val;
                m = fmaxf(m, val);
            }
            float wsum = 0.f;
            #pragma unroll
            for (int r = 0; r < 9; ++r) {
                float e = __expf(w[r] - m);
                w[r] = e;
                wsum += e;
            }
            float inv = 1.0f / wsum;
            #pragma unroll
            for (int r = 0; r < 9; ++r) {
                int dy = r / 3 - 1, dx = r % 3 - 1;
                int ny = y + dy, nx = xx + dx;
                bool inb = (ny >= 0) && (ny < HT) && (nx >= 0) && (nx < WI);
                w[r] = inb ? (w[r] * inv) : 0.0f;
            }

            float o[16];
            #pragma unroll
            for (int j2 = 0; j2 < 16; ++j2) o[j2] = 0.f;
            #pragma unroll
            for (int r = 0; r < 9; ++r) {
                int dy = r / 3 - 1, dx = r % 3 - 1;
                int hp = (ly + 1 + dy) * 26 + lx + 1 + dx;
                const unsigned short* vp = &Vt[hp * 40 + hg * 16];
                short8 v8a = *(const short8*)&vp[0];
                short8 v8b = *(const short8*)&vp[8];
                #pragma unroll
                for (int j2 = 0; j2 < 8; ++j2) {
                    o[j2]     = fmaf(w[r], b2f((unsigned short)v8a[j2]), o[j2]);
                    o[8 + j2] = fmaf(w[r], b2f((unsigned short)v8b[j2]), o[8 + j2]);
                }
            }
            float* op = out + (size_t)(head * DKH + hg * 16) * HW_ + y * WI + xx;
            #pragma unroll
            for (int j2 = 0; j2 < 16; ++j2)
                op[(size_t)j2 * HW_] = o[j2];
        }
        __syncthreads();                       // gather done before next epilogue
    }
}

// ---------------------------------------------------------------------------
// Workspace layout:
//   [0, 196608)  wqkv : 8*96*128 bf16        (vbuf/sbuf eliminated)
// ---------------------------------------------------------------------------
extern "C" void kernel_launch(void* const* d_in, const int* in_sizes, int n_in,
                              void* d_out, int out_size, void* d_ws, size_t ws_size,
                              hipStream_t stream) {
    const float* x  = (const float*)d_in[0];
    const float* wq = (const float*)d_in[1];
    const float* wk = (const float*)d_in[2];
    const float* wv = (const float*)d_in[3];

    unsigned short* wqkv = (unsigned short*)d_ws;

    convw_kernel<<<384, 256, 0, stream>>>(wq, wk, wv, wqkv);
    fusedattn_kernel<<<512, 256, 0, stream>>>(x, wqkv, (float*)d_out);
}